// Round 6
// baseline (239.439 us; speedup 1.0000x reference)
//
#include <hip/hip_runtime.h>
#include <math.h>

#define B_SZ 2
#define T_LEN 1024
#define D_MODEL 1024
#define D_STATE 16
#define D_INNER 2048
#define DT_RANK 64
#define NTOK (B_SZ * T_LEN)               // 2048 tokens
#define XPROJ_OUT 96
#define XPROJ_LD 128                      // padded leading dim for dbc
#define NCHUNK 32
#define CHUNK_L (T_LEN / NCHUNK)          // 32
#define NSPLIT 16                         // split-K for x_proj (K-slab 128)

typedef __attribute__((ext_vector_type(8))) short bf16x8;
typedef __attribute__((ext_vector_type(4))) float f32x4;

__device__ __forceinline__ float sigmoidf_(float x) { return 1.f / (1.f + __expf(-x)); }

__device__ __forceinline__ unsigned f2bf_u(float f) {  // RNE f32->bf16 bits
    unsigned u = __float_as_uint(f);
    return (u + 0x7FFFu + ((u >> 16) & 1u)) >> 16;
}
__device__ __forceinline__ float bf2f(unsigned short u) {
    return __uint_as_float((unsigned)u << 16);
}

__device__ __forceinline__ void gload_lds16(const void* g, void* l) {
    __builtin_amdgcn_global_load_lds((const __attribute__((address_space(1))) unsigned*)g,
                                     (__attribute__((address_space(3))) unsigned*)l,
                                     16, 0, 0);
}

// ---------------- fused prep: RMSNorm + all weight casts, one launch ----------------
__global__ __launch_bounds__(256) void k_prep(const float* __restrict__ x,
                                              const float* __restrict__ norm_w,
                                              const float* __restrict__ w_in,
                                              const float* __restrict__ w_out,
                                              const float* __restrict__ w_x,
                                              const float* __restrict__ w_dt,
                                              unsigned short* __restrict__ xn,
                                              unsigned* __restrict__ wib,
                                              unsigned* __restrict__ wob,
                                              unsigned* __restrict__ wxb,
                                              unsigned* __restrict__ wdtb) {
    __shared__ float red[4];
    int blk = blockIdx.x;
    if (blk < 2048) {  // RMSNorm row
        const float* xr = x + (size_t)blk * D_MODEL;
        int i = threadIdx.x * 4;
        float4 xv = *(const float4*)(xr + i);
        float s = xv.x * xv.x + xv.y * xv.y + xv.z * xv.z + xv.w * xv.w;
#pragma unroll
        for (int m = 1; m <= 32; m <<= 1) s += __shfl_xor(s, m);
        if ((threadIdx.x & 63) == 0) red[threadIdx.x >> 6] = s;
        __syncthreads();
        float tot = red[0] + red[1] + red[2] + red[3];
        float scale = rsqrtf(tot * (1.f / D_MODEL) + 1.1920929e-07f);
        float4 wv = *(const float4*)(norm_w + i);
        uint2 o;
        o.x = f2bf_u(xv.x * scale * wv.x) | (f2bf_u(xv.y * scale * wv.y) << 16);
        o.y = f2bf_u(xv.z * scale * wv.z) | (f2bf_u(xv.w * scale * wv.w) << 16);
        *(uint2*)(xn + (size_t)blk * D_MODEL + i) = o;
        return;
    }
    blk -= 2048;
    const float* src;
    unsigned* dst;
    int lidx;  // index in units of 8 elems
    if (blk < 2048) {
        src = w_in; dst = wib; lidx = blk * 256 + threadIdx.x;
    } else if (blk < 3072) {
        src = w_out; dst = wob; lidx = (blk - 2048) * 256 + threadIdx.x;
    } else if (blk < 3200) {
        dst = wxb; lidx = (blk - 3072) * 256 + threadIdx.x;
        if (lidx * 8 >= 96 * 2048) {  // pad rows 96..127 with zeros
            uint4 z = {0, 0, 0, 0};
            ((uint4*)dst)[lidx] = z;
            return;
        }
        src = w_x;
    } else {
        src = w_dt; dst = wdtb; lidx = (blk - 3200) * 256 + threadIdx.x;
    }
    float4 a = ((const float4*)src)[lidx * 2];
    float4 b = ((const float4*)src)[lidx * 2 + 1];
    uint4 o;
    o.x = f2bf_u(a.x) | (f2bf_u(a.y) << 16);
    o.y = f2bf_u(a.z) | (f2bf_u(a.w) << 16);
    o.z = f2bf_u(b.x) | (f2bf_u(b.y) << 16);
    o.w = f2bf_u(b.z) | (f2bf_u(b.w) << 16);
    ((uint4*)dst)[lidx] = o;
}

// XOR-swizzled LDS tile layout (rows of 64 bf16 = 8 chunks of 16B):
//   slot(r, c) = r*8 + (c ^ (r & 7))   — spreads fragment reads over all 32 banks.

// ---------------- bf16 MFMA GEMM, BM=128, BK=64, double-buffered K-loop ----------------
// EPI: 0 = f32 out, + per-element residual res[row*ldc+col]
//      1 = softplus(v + res[col]) bf16 out; 3 = bf16 out, silu when n0 >= D_INNER.
template <int BN, int CW, int EPI>
__global__ __launch_bounds__(256) void gemm_bf16(const unsigned short* __restrict__ A,
                                                 const unsigned short* __restrict__ B,
                                                 void* __restrict__ Cv, int ldc, int K,
                                                 const float* __restrict__ res) {
    constexpr int RW = 4 / CW;
    constexpr int MI = (128 / RW) / 16;
    constexpr int NJ = (BN / CW) / 16;
    __shared__ __align__(16) unsigned short As[2][128 * 64];
    __shared__ __align__(16) unsigned short Bs[2][BN * 64];
    int tid = threadIdx.x;
    int lane = tid & 63, wv = tid >> 6;
    int wr = wv / CW, wc = wv % CW;
    int lm = lane & 15, q = lane >> 4;
    int sw = lm & 7;
    int m0 = blockIdx.x * 128, n0 = blockIdx.y * BN;
    f32x4 acc[MI][NJ] = {};

    auto stage = [&](int bufi, int k0) {
#pragma unroll
        for (int it = 0; it < 4; ++it) {
            int chunk = it * 256 + tid;
            int cc = (chunk & 7) ^ ((chunk >> 3) & 7);  // swizzled source column-chunk
            const unsigned short* g = A + (size_t)(m0 + (chunk >> 3)) * K + k0 + cc * 8;
            char* l = (char*)As[bufi] + (it * 256 + wv * 64) * 16 + lane * 16;
            gload_lds16(g, l);
        }
#pragma unroll
        for (int it = 0; it < BN / 32; ++it) {
            int chunk = it * 256 + tid;
            int cc = (chunk & 7) ^ ((chunk >> 3) & 7);
            const unsigned short* g = B + (size_t)(n0 + (chunk >> 3)) * K + k0 + cc * 8;
            char* l = (char*)Bs[bufi] + (it * 256 + wv * 64) * 16 + lane * 16;
            gload_lds16(g, l);
        }
    };

    stage(0, 0);
    __syncthreads();  // drains vmcnt(0) for buf0
    int cur = 0;
    for (int k0 = 0; k0 < K; k0 += 64) {
        if (k0 + 64 < K) stage(cur ^ 1, k0 + 64);  // prefetch overlaps compute below
        const unsigned short* Ac = As[cur];
        const unsigned short* Bc = Bs[cur];
#pragma unroll
        for (int h = 0; h < 2; ++h) {
            bf16x8 af[MI], bfr[NJ];
#pragma unroll
            for (int i = 0; i < MI; ++i)
                af[i] = *(const bf16x8*)(Ac + (wr * MI * 16 + i * 16 + lm) * 64 +
                                         (((h << 2) + q) ^ sw) * 8);
#pragma unroll
            for (int j = 0; j < NJ; ++j)
                bfr[j] = *(const bf16x8*)(Bc + (wc * NJ * 16 + j * 16 + lm) * 64 +
                                          (((h << 2) + q) ^ sw) * 8);
#pragma unroll
            for (int i = 0; i < MI; ++i)
#pragma unroll
                for (int j = 0; j < NJ; ++j)
                    acc[i][j] = __builtin_amdgcn_mfma_f32_16x16x32_bf16(af[i], bfr[j], acc[i][j], 0, 0, 0);
        }
        __syncthreads();  // drains prefetch vmcnt + release cur buffer
        cur ^= 1;
    }
#pragma unroll
    for (int i = 0; i < MI; ++i) {
#pragma unroll
        for (int j = 0; j < NJ; ++j) {
#pragma unroll
            for (int r = 0; r < 4; ++r) {
                int row = m0 + wr * MI * 16 + i * 16 + q * 4 + r;
                int col = n0 + wc * NJ * 16 + j * 16 + lm;
                float v = acc[i][j][r];
                if (EPI == 0) {  // f32 out + full residual (out_proj)
                    ((float*)Cv)[(size_t)row * ldc + col] = v + res[(size_t)row * ldc + col];
                } else if (EPI == 1) {
                    v += res[col];
                    v = (v > 20.f) ? v : log1pf(__expf(v));
                    ((unsigned short*)Cv)[(size_t)row * ldc + col] = (unsigned short)f2bf_u(v);
                } else {  // EPI == 3
                    if (n0 >= D_INNER) v = v * sigmoidf_(v);  // fused silu(z)
                    ((unsigned short*)Cv)[(size_t)row * ldc + col] = (unsigned short)f2bf_u(v);
                }
            }
        }
    }
}

// ---------------- x_proj split-K MFMA GEMM (K-slab 128, 2 K-steps, dbuf) -> bf16 partials ----------------
__global__ __launch_bounds__(256) void xproj_gemm(const unsigned short* __restrict__ A,
                                                  const unsigned short* __restrict__ B,
                                                  unsigned short* __restrict__ part) {
    constexpr int MI = 4, NJ = 4;
    __shared__ __align__(16) unsigned short As[2][128 * 64];
    __shared__ __align__(16) unsigned short Bs[2][128 * 64];
    int tid = threadIdx.x;
    int lane = tid & 63, wv = tid >> 6;
    int wr = wv >> 1, wc = wv & 1;
    int lm = lane & 15, q = lane >> 4;
    int sw = lm & 7;
    int m0 = blockIdx.x * 128;
    int kbase = blockIdx.y * 128;
    f32x4 acc[MI][NJ] = {};

    auto stage = [&](int bufi, int k0) {
#pragma unroll
        for (int it = 0; it < 4; ++it) {
            int chunk = it * 256 + tid;
            int cc = (chunk & 7) ^ ((chunk >> 3) & 7);
            const unsigned short* g = A + (size_t)(m0 + (chunk >> 3)) * D_INNER + k0 + cc * 8;
            char* l = (char*)As[bufi] + (it * 256 + wv * 64) * 16 + lane * 16;
            gload_lds16(g, l);
        }
#pragma unroll
        for (int it = 0; it < 4; ++it) {
            int chunk = it * 256 + tid;
            int cc = (chunk & 7) ^ ((chunk >> 3) & 7);
            const unsigned short* g = B + (size_t)(chunk >> 3) * D_INNER + k0 + cc * 8;
            char* l = (char*)Bs[bufi] + (it * 256 + wv * 64) * 16 + lane * 16;
            gload_lds16(g, l);
        }
    };

    stage(0, kbase);
    __syncthreads();
    for (int ks = 0; ks < 2; ++ks) {
        if (ks == 0) stage(1, kbase + 64);
        const unsigned short* Ac = As[ks];
        const unsigned short* Bc = Bs[ks];
#pragma unroll
        for (int h = 0; h < 2; ++h) {
            bf16x8 af[MI], bfr[NJ];
#pragma unroll
            for (int i = 0; i < MI; ++i)
                af[i] = *(const bf16x8*)(Ac + (wr * 64 + i * 16 + lm) * 64 + (((h << 2) + q) ^ sw) * 8);
#pragma unroll
            for (int j = 0; j < NJ; ++j)
                bfr[j] = *(const bf16x8*)(Bc + (wc * 64 + j * 16 + lm) * 64 + (((h << 2) + q) ^ sw) * 8);
#pragma unroll
            for (int i = 0; i < MI; ++i)
#pragma unroll
                for (int j = 0; j < NJ; ++j)
                    acc[i][j] = __builtin_amdgcn_mfma_f32_16x16x32_bf16(af[i], bfr[j], acc[i][j], 0, 0, 0);
        }
        __syncthreads();
    }
    unsigned short* dst = part + (size_t)blockIdx.y * (NTOK * XPROJ_LD);
#pragma unroll
    for (int i = 0; i < MI; ++i)
#pragma unroll
        for (int j = 0; j < NJ; ++j)
#pragma unroll
            for (int r = 0; r < 4; ++r) {
                int row = m0 + wr * 64 + i * 16 + q * 4 + r;
                int col = wc * 64 + j * 16 + lm;
                dst[(size_t)row * XPROJ_LD + col] = (unsigned short)f2bf_u(acc[i][j][r]);
            }
}

// ---------------- reduce split-K partials (4 elems/thread); emit dbc f32 + dt_raw bf16 ----------------
__global__ __launch_bounds__(256) void k_xred(const unsigned short* __restrict__ part,
                                              float* __restrict__ dbc,
                                              unsigned short* __restrict__ dtrawb) {
    int idx4 = blockIdx.x * 256 + threadIdx.x;  // unit of 4 elems
    float s0 = 0.f, s1 = 0.f, s2 = 0.f, s3 = 0.f;
#pragma unroll
    for (int sp = 0; sp < NSPLIT; ++sp) {
        uint2 v = *(const uint2*)(part + (size_t)sp * (NTOK * XPROJ_LD) + idx4 * 4);
        s0 += __uint_as_float(v.x << 16);
        s1 += __uint_as_float(v.x & 0xFFFF0000u);
        s2 += __uint_as_float(v.y << 16);
        s3 += __uint_as_float(v.y & 0xFFFF0000u);
    }
    float4 sv = {s0, s1, s2, s3};
    *(float4*)(dbc + idx4 * 4) = sv;
    int col = (idx4 * 4) & (XPROJ_LD - 1);
    if (col < DT_RANK) {
        int row = (idx4 * 4) >> 7;
        uint2 o;
        o.x = f2bf_u(s0) | (f2bf_u(s1) << 16);
        o.y = f2bf_u(s2) | (f2bf_u(s3) << 16);
        *(uint2*)(dtrawb + (size_t)row * DT_RANK + col) = o;
    }
}

// ---------------- depthwise causal conv (k=4, bf16 in) + SiLU -> ub, 4 channels/thread ----------------
__global__ __launch_bounds__(256) void k_conv(const unsigned short* __restrict__ xz,
                                              const float* __restrict__ cw,
                                              const float* __restrict__ cb,
                                              unsigned short* __restrict__ ub) {
    int idx = blockIdx.x * 256 + threadIdx.x;
    int c4 = (idx & (D_INNER / 4 - 1)) * 4;
    int t = (idx >> 9) & (T_LEN - 1);
    int b = idx >> 19;
    const unsigned short* xs = xz + (size_t)b * T_LEN * 2 * D_INNER + c4;
    float4 w[4];
#pragma unroll
    for (int i = 0; i < 4; ++i) w[i] = ((const float4*)cw)[c4 + i];
    float4 cbv = *(const float4*)(cb + c4);
    float s[4] = {cbv.x, cbv.y, cbv.z, cbv.w};
#pragma unroll
    for (int k = 0; k < 4; ++k) {
        int tt = t - 3 + k;
        if (tt >= 0) {
            ushort4 xv = *(const ushort4*)(xs + (size_t)tt * 2 * D_INNER);
            float fx0 = bf2f(xv.x), fx1 = bf2f(xv.y), fx2 = bf2f(xv.z), fx3 = bf2f(xv.w);
            float w0 = (k == 0) ? w[0].x : (k == 1) ? w[0].y : (k == 2) ? w[0].z : w[0].w;
            float w1 = (k == 0) ? w[1].x : (k == 1) ? w[1].y : (k == 2) ? w[1].z : w[1].w;
            float w2 = (k == 0) ? w[2].x : (k == 1) ? w[2].y : (k == 2) ? w[2].z : w[2].w;
            float w3 = (k == 0) ? w[3].x : (k == 1) ? w[3].y : (k == 2) ? w[3].z : w[3].w;
            s[0] = fmaf(fx0, w0, s[0]);
            s[1] = fmaf(fx1, w1, s[1]);
            s[2] = fmaf(fx2, w2, s[2]);
            s[3] = fmaf(fx3, w3, s[3]);
        }
    }
    ushort4 o;
    o.x = (unsigned short)f2bf_u(s[0] * sigmoidf_(s[0]));
    o.y = (unsigned short)f2bf_u(s[1] * sigmoidf_(s[1]));
    o.z = (unsigned short)f2bf_u(s[2] * sigmoidf_(s[2]));
    o.w = (unsigned short)f2bf_u(s[3] * sigmoidf_(s[3]));
    *(ushort4*)(ub + (size_t)(b * T_LEN + t) * D_INNER + c4) = o;
}

// ---------------- chunked selective scan, state-parallel: 4 threads/channel ----------------
// Block: 64 channels x 32-t chunk; thread (cl, sq) owns 4 states. Serial exp chain per
// thread drops 512 -> 128; grid 2048 blocks = 8/CU (full wave occupancy).
__global__ __launch_bounds__(256) void k_scan1(const unsigned short* __restrict__ delta,
                                               const unsigned short* __restrict__ ub,
                                               const float* __restrict__ dbc,
                                               const float* __restrict__ A_log,
                                               float* __restrict__ Pbuf,
                                               float* __restrict__ Hbuf) {
    int tid = threadIdx.x;
    int cl = tid >> 2, sq = tid & 3;
    int c0 = blockIdx.x * 64;
    int c = c0 + cl;
    int b = blockIdx.y >> 5, chunk = blockIdx.y & 31;
    int t0 = chunk * CHUNK_L;
    __shared__ float bc[CHUNK_L][32];  // [t][0:16]=B, [t][16:32]=C
    __shared__ __align__(16) unsigned short sd[CHUNK_L][64];
    __shared__ __align__(16) unsigned short su[CHUNK_L][64];
    {
        int t = tid >> 3, col = (tid & 7) * 4;
        const float* src = dbc + ((size_t)b * T_LEN + t0 + t) * XPROJ_LD + DT_RANK + col;
        *(float4*)&bc[t][col] = *(const float4*)src;
    }
    {
        int r = tid >> 3, c8 = (tid & 7) * 8;
        const unsigned short* dp0 = delta + ((size_t)b * T_LEN + t0) * D_INNER + c0;
        const unsigned short* up0 = ub + ((size_t)b * T_LEN + t0) * D_INNER + c0;
        *(uint4*)&sd[r][c8] = *(const uint4*)(dp0 + (size_t)r * D_INNER + c8);
        *(uint4*)&su[r][c8] = *(const uint4*)(up0 + (size_t)r * D_INNER + c8);
    }
    __syncthreads();
    float4 av = *(const float4*)(A_log + (size_t)c * D_STATE + sq * 4);
    float A0 = -__expf(av.x), A1 = -__expf(av.y), A2 = -__expf(av.z), A3 = -__expf(av.w);
    float h0 = 0.f, h1 = 0.f, h2 = 0.f, h3 = 0.f, sumd = 0.f;
#pragma unroll 4
    for (int t = 0; t < CHUNK_L; ++t) {
        float dv = bf2f(sd[t][cl]);
        float uv = bf2f(su[t][cl]);
        float du = dv * uv;
        sumd += dv;
        float4 Bv = *(const float4*)&bc[t][sq * 4];
        h0 = fmaf(__expf(dv * A0), h0, du * Bv.x);
        h1 = fmaf(__expf(dv * A1), h1, du * Bv.y);
        h2 = fmaf(__expf(dv * A2), h2, du * Bv.z);
        h3 = fmaf(__expf(dv * A3), h3, du * Bv.w);
    }
    size_t o = ((size_t)((b * NCHUNK + chunk) * D_INNER) + c) * 16 + sq * 4;
    float4 hv = {h0, h1, h2, h3};
    *(float4*)(Hbuf + o) = hv;
    float4 pv = {__expf(A0 * sumd), __expf(A1 * sumd), __expf(A2 * sumd), __expf(A3 * sumd)};
    *(float4*)(Pbuf + o) = pv;
}

__global__ __launch_bounds__(256) void k_scan2(const float* __restrict__ Pbuf,
                                               const float* __restrict__ Hbuf,
                                               float* __restrict__ Sbuf) {
    int idx = blockIdx.x * 256 + threadIdx.x;  // 0..65535 = (b, c*16+s)
    int b = idx >> 15, r = idx & 32767;
    size_t base = (size_t)b * NCHUNK * (D_INNER * 16) + r;
    float p[NCHUNK], hl[NCHUNK];
#pragma unroll
    for (int ch = 0; ch < NCHUNK; ++ch) {
        size_t o = base + (size_t)ch * (D_INNER * 16);
        p[ch] = Pbuf[o];
        hl[ch] = Hbuf[o];
    }
    float h = 0.f;
#pragma unroll
    for (int ch = 0; ch < NCHUNK; ++ch) {
        Sbuf[base + (size_t)ch * (D_INNER * 16)] = h;
        h = fmaf(p[ch], h, hl[ch]);
    }
}

__global__ __launch_bounds__(256) void k_scan3(const unsigned short* __restrict__ delta,
                                               const unsigned short* __restrict__ ub,
                                               const float* __restrict__ dbc,
                                               const unsigned short* __restrict__ xz,  // z-half pre-silu'd
                                               const float* __restrict__ A_log,
                                               const float* __restrict__ Dp,
                                               const float* __restrict__ Sbuf,
                                               unsigned short* __restrict__ yb) {
    int tid = threadIdx.x;
    int cl = tid >> 2, sq = tid & 3;
    int c0 = blockIdx.x * 64;
    int c = c0 + cl;
    int b = blockIdx.y >> 5, chunk = blockIdx.y & 31;
    int t0 = chunk * CHUNK_L;
    __shared__ float bc[CHUNK_L][32];
    __shared__ __align__(16) unsigned short sd[CHUNK_L][64];
    __shared__ __align__(16) unsigned short su[CHUNK_L][64];
    __shared__ __align__(16) unsigned short szy[CHUNK_L][64];  // z in, y out (in-place)
    {
        int t = tid >> 3, col = (tid & 7) * 4;
        const float* src = dbc + ((size_t)b * T_LEN + t0 + t) * XPROJ_LD + DT_RANK + col;
        *(float4*)&bc[t][col] = *(const float4*)src;
    }
    int r = tid >> 3, c8 = (tid & 7) * 8;
    {
        const unsigned short* dp0 = delta + ((size_t)b * T_LEN + t0) * D_INNER + c0;
        const unsigned short* up0 = ub + ((size_t)b * T_LEN + t0) * D_INNER + c0;
        const unsigned short* zp0 = xz + ((size_t)b * T_LEN + t0) * 2 * D_INNER + D_INNER + c0;
        *(uint4*)&sd[r][c8] = *(const uint4*)(dp0 + (size_t)r * D_INNER + c8);
        *(uint4*)&su[r][c8] = *(const uint4*)(up0 + (size_t)r * D_INNER + c8);
        *(uint4*)&szy[r][c8] = *(const uint4*)(zp0 + (size_t)r * 2 * D_INNER + c8);
    }
    __syncthreads();
    float4 av = *(const float4*)(A_log + (size_t)c * D_STATE + sq * 4);
    float A0 = -__expf(av.x), A1 = -__expf(av.y), A2 = -__expf(av.z), A3 = -__expf(av.w);
    float Dc = Dp[c];
    size_t ho = ((size_t)((b * NCHUNK + chunk) * D_INNER) + c) * 16 + sq * 4;
    float4 hv = *(const float4*)(Sbuf + ho);
    float h0 = hv.x, h1 = hv.y, h2 = hv.z, h3 = hv.w;
#pragma unroll 2
    for (int t = 0; t < CHUNK_L; ++t) {
        float dv = bf2f(sd[t][cl]);
        float uv = bf2f(su[t][cl]);
        float du = dv * uv;
        float4 Bv = *(const float4*)&bc[t][sq * 4];
        float4 Cv = *(const float4*)&bc[t][16 + sq * 4];
        h0 = fmaf(__expf(dv * A0), h0, du * Bv.x);
        h1 = fmaf(__expf(dv * A1), h1, du * Bv.y);
        h2 = fmaf(__expf(dv * A2), h2, du * Bv.z);
        h3 = fmaf(__expf(dv * A3), h3, du * Bv.w);
        float yp = h0 * Cv.x + h1 * Cv.y + h2 * Cv.z + h3 * Cv.w;
        yp += __shfl_xor(yp, 1);
        yp += __shfl_xor(yp, 2);
        if (sq == 0) {
            float sz = bf2f(szy[t][cl]);  // already silu(z)
            szy[t][cl] = (unsigned short)f2bf_u((yp + Dc * uv) * sz);
        }
    }
    __syncthreads();
    {
        unsigned short* yp0 = yb + ((size_t)b * T_LEN + t0) * D_INNER + c0;
        *(uint4*)(yp0 + (size_t)r * D_INNER + c8) = *(uint4*)&szy[r][c8];
    }
}

extern "C" void kernel_launch(void* const* d_in, const int* in_sizes, int n_in,
                              void* d_out, int out_size, void* d_ws, size_t ws_size,
                              hipStream_t stream) {
    const float* x         = (const float*)d_in[0];
    const float* norm_w    = (const float*)d_in[1];
    const float* in_proj_w = (const float*)d_in[2];
    const float* conv_w    = (const float*)d_in[3];
    const float* conv_b    = (const float*)d_in[4];
    const float* x_proj_w  = (const float*)d_in[5];
    const float* dt_proj_w = (const float*)d_in[6];
    const float* dt_proj_b = (const float*)d_in[7];
    const float* A_log     = (const float*)d_in[8];
    const float* D_param   = (const float*)d_in[9];
    const float* out_proj_w= (const float*)d_in[10];
    float* out = (float*)d_out;

    // workspace layout (float units), flat
    float* ws = (float*)d_ws;
    unsigned short* xzb    = (unsigned short*)(ws);            // 2048*4096 bf16 (z-half silu'd)
    unsigned short* ub     = (unsigned short*)(ws + 4194304);  // 2048*2048 bf16
    unsigned short* yb     = (unsigned short*)(ws + 6291456);  // 2048*2048 bf16
    unsigned short* partb  = (unsigned short*)(ws + 8388608);  // 16*2048*128 bf16
    float*          dbc    = ws + 12582912;                    // 2048*128 f32
    unsigned short* deltab = (unsigned short*)(ws + 12845056); // 2048*2048 bf16
    float*          Pbuf   = ws + 14942208;                    // 2*32*2048*16 f32
    float*          Hbuf   = ws + 17039360;                    // 2*32*2048*16 f32
    float*          Sbuf   = ws + 19136512;                    // 2*32*2048*16 f32
    unsigned short* wib    = (unsigned short*)(ws + 21233664); // 4096*1024 bf16
    unsigned short* wob    = (unsigned short*)(ws + 23330816); // 1024*2048 bf16
    unsigned short* wxb    = (unsigned short*)(ws + 24379392); // 128*2048 bf16
    unsigned short* wdtb   = (unsigned short*)(ws + 24510464); // 2048*64 bf16
    unsigned short* dtrawb = (unsigned short*)(ws + 24576000); // 2048*64 bf16
    unsigned short* xnb    = (unsigned short*)(ws + 24641536); // 2048*1024 bf16

    // 0. fused RMSNorm + all weight casts (one launch)
    k_prep<<<5312, 256, 0, stream>>>(x, norm_w, in_proj_w, out_proj_w, x_proj_w, dt_proj_w,
                                     xnb, (unsigned*)wib, (unsigned*)wob, (unsigned*)wxb,
                                     (unsigned*)wdtb);
    // 1. xz = xn @ in_proj_w^T (2048x4096x1024) -> bf16; z-half fused silu (512 blocks)
    gemm_bf16<128, 2, 3><<<dim3(NTOK / 128, 4096 / 128), 256, 0, stream>>>(
        xnb, wib, xzb, 2 * D_INNER, D_MODEL, nullptr);
    // 2. depthwise conv + SiLU -> ub (4 channels/thread, 8B/lane)
    k_conv<<<(NTOK * D_INNER / 4) / 256, 256, 0, stream>>>(xzb, conv_w, conv_b, ub);
    // 3. x_dbc: split-K MFMA GEMM (16 slabs of K=128, 256 blocks, dbuf) + reduce
    xproj_gemm<<<dim3(NTOK / 128, NSPLIT), 256, 0, stream>>>(ub, wxb, partb);
    k_xred<<<(NTOK * XPROJ_LD) / 1024, 256, 0, stream>>>(partb, dbc, dtrawb);
    // 4. delta = softplus(dt_raw @ dt_proj_w^T + b) -> bf16 (BN=64: 512 blocks)
    gemm_bf16<64, 1, 1><<<dim3(NTOK / 128, D_INNER / 64), 256, 0, stream>>>(
        dtrawb, wdtb, deltab, D_INNER, DT_RANK, dt_proj_b);
    // 5. chunked selective scan (3 kernels, state-parallel 4 thr/channel) -> yb
    k_scan1<<<dim3(D_INNER / 64, B_SZ * NCHUNK), 256, 0, stream>>>(deltab, ub, dbc, A_log,
                                                                   Pbuf, Hbuf);
    k_scan2<<<(B_SZ * D_INNER * D_STATE) / 256, 256, 0, stream>>>(Pbuf, Hbuf, Sbuf);
    k_scan3<<<dim3(D_INNER / 64, B_SZ * NCHUNK), 256, 0, stream>>>(deltab, ub, dbc, xzb, A_log,
                                                                   D_param, Sbuf, yb);
    // 6. out = y @ out_proj_w^T + x (2048x1024x2048), 128x64 tiles, dbuf pipeline
    gemm_bf16<64, 2, 0><<<dim3(NTOK / 128, D_MODEL / 64), 256, 0, stream>>>(
        yb, wob, (void*)out, D_MODEL, D_INNER, x);

    (void)in_sizes; (void)n_in; (void)out_size; (void)ws_size;
}

// Round 7
// 224.814 us; speedup vs baseline: 1.0651x; 1.0651x over previous
//
#include <hip/hip_runtime.h>
#include <math.h>

#define B_SZ 2
#define T_LEN 1024
#define D_MODEL 1024
#define D_STATE 16
#define D_INNER 2048
#define DT_RANK 64
#define NTOK (B_SZ * T_LEN)               // 2048 tokens
#define XPROJ_OUT 96
#define XPROJ_LD 128                      // padded leading dim for dbc
#define NCHUNK 32
#define CHUNK_L (T_LEN / NCHUNK)          // 32
#define NSPLIT 16                         // split-K for x_proj (K-slab 128)

typedef __attribute__((ext_vector_type(8))) short bf16x8;
typedef __attribute__((ext_vector_type(4))) float f32x4;

__device__ __forceinline__ float sigmoidf_(float x) { return 1.f / (1.f + __expf(-x)); }

__device__ __forceinline__ unsigned f2bf_u(float f) {  // RNE f32->bf16 bits
    unsigned u = __float_as_uint(f);
    return (u + 0x7FFFu + ((u >> 16) & 1u)) >> 16;
}
__device__ __forceinline__ float bf2f(unsigned short u) {
    return __uint_as_float((unsigned)u << 16);
}

__device__ __forceinline__ void gload_lds16(const void* g, void* l) {
    __builtin_amdgcn_global_load_lds((const __attribute__((address_space(1))) unsigned*)g,
                                     (__attribute__((address_space(3))) unsigned*)l,
                                     16, 0, 0);
}

// ---------------- fused prep: RMSNorm + all weight casts, one launch ----------------
__global__ __launch_bounds__(256) void k_prep(const float* __restrict__ x,
                                              const float* __restrict__ norm_w,
                                              const float* __restrict__ w_in,
                                              const float* __restrict__ w_out,
                                              const float* __restrict__ w_x,
                                              const float* __restrict__ w_dt,
                                              unsigned short* __restrict__ xn,
                                              unsigned* __restrict__ wib,
                                              unsigned* __restrict__ wob,
                                              unsigned* __restrict__ wxb,
                                              unsigned* __restrict__ wdtb) {
    __shared__ float red[4];
    int blk = blockIdx.x;
    if (blk < 2048) {  // RMSNorm row
        const float* xr = x + (size_t)blk * D_MODEL;
        int i = threadIdx.x * 4;
        float4 xv = *(const float4*)(xr + i);
        float s = xv.x * xv.x + xv.y * xv.y + xv.z * xv.z + xv.w * xv.w;
#pragma unroll
        for (int m = 1; m <= 32; m <<= 1) s += __shfl_xor(s, m);
        if ((threadIdx.x & 63) == 0) red[threadIdx.x >> 6] = s;
        __syncthreads();
        float tot = red[0] + red[1] + red[2] + red[3];
        float scale = rsqrtf(tot * (1.f / D_MODEL) + 1.1920929e-07f);
        float4 wv = *(const float4*)(norm_w + i);
        uint2 o;
        o.x = f2bf_u(xv.x * scale * wv.x) | (f2bf_u(xv.y * scale * wv.y) << 16);
        o.y = f2bf_u(xv.z * scale * wv.z) | (f2bf_u(xv.w * scale * wv.w) << 16);
        *(uint2*)(xn + (size_t)blk * D_MODEL + i) = o;
        return;
    }
    blk -= 2048;
    const float* src;
    unsigned* dst;
    int lidx;  // index in units of 8 elems
    if (blk < 2048) {
        src = w_in; dst = wib; lidx = blk * 256 + threadIdx.x;
    } else if (blk < 3072) {
        src = w_out; dst = wob; lidx = (blk - 2048) * 256 + threadIdx.x;
    } else if (blk < 3200) {
        dst = wxb; lidx = (blk - 3072) * 256 + threadIdx.x;
        if (lidx * 8 >= 96 * 2048) {  // pad rows 96..127 with zeros
            uint4 z = {0, 0, 0, 0};
            ((uint4*)dst)[lidx] = z;
            return;
        }
        src = w_x;
    } else {
        src = w_dt; dst = wdtb; lidx = (blk - 3200) * 256 + threadIdx.x;
    }
    float4 a = ((const float4*)src)[lidx * 2];
    float4 b = ((const float4*)src)[lidx * 2 + 1];
    uint4 o;
    o.x = f2bf_u(a.x) | (f2bf_u(a.y) << 16);
    o.y = f2bf_u(a.z) | (f2bf_u(a.w) << 16);
    o.z = f2bf_u(b.x) | (f2bf_u(b.y) << 16);
    o.w = f2bf_u(b.z) | (f2bf_u(b.w) << 16);
    ((uint4*)dst)[lidx] = o;
}

// XOR-swizzled LDS tile layout (rows of 64 bf16 = 8 chunks of 16B):
//   slot(r, c) = r*8 + (c ^ (r & 7))   — spreads fragment reads over all 32 banks.

// ---------------- bf16 MFMA GEMM, BM=128, BK=64, double-buffered K-loop ----------------
// EPI: 0 = f32 out, + per-element residual res[row*ldc+col]
//      1 = softplus(v + res[col]) bf16 out; 3 = bf16 out, silu when n0 >= D_INNER.
template <int BN, int CW, int EPI>
__global__ __launch_bounds__(256) void gemm_bf16(const unsigned short* __restrict__ A,
                                                 const unsigned short* __restrict__ B,
                                                 void* __restrict__ Cv, int ldc, int K,
                                                 const float* __restrict__ res) {
    constexpr int RW = 4 / CW;
    constexpr int MI = (128 / RW) / 16;
    constexpr int NJ = (BN / CW) / 16;
    __shared__ __align__(16) unsigned short As[2][128 * 64];
    __shared__ __align__(16) unsigned short Bs[2][BN * 64];
    int tid = threadIdx.x;
    int lane = tid & 63, wv = tid >> 6;
    int wr = wv / CW, wc = wv % CW;
    int lm = lane & 15, q = lane >> 4;
    int sw = lm & 7;
    int m0 = blockIdx.x * 128, n0 = blockIdx.y * BN;
    f32x4 acc[MI][NJ] = {};

    auto stage = [&](int bufi, int k0) {
#pragma unroll
        for (int it = 0; it < 4; ++it) {
            int chunk = it * 256 + tid;
            int cc = (chunk & 7) ^ ((chunk >> 3) & 7);  // swizzled source column-chunk
            const unsigned short* g = A + (size_t)(m0 + (chunk >> 3)) * K + k0 + cc * 8;
            char* l = (char*)As[bufi] + (it * 256 + wv * 64) * 16 + lane * 16;
            gload_lds16(g, l);
        }
#pragma unroll
        for (int it = 0; it < BN / 32; ++it) {
            int chunk = it * 256 + tid;
            int cc = (chunk & 7) ^ ((chunk >> 3) & 7);
            const unsigned short* g = B + (size_t)(n0 + (chunk >> 3)) * K + k0 + cc * 8;
            char* l = (char*)Bs[bufi] + (it * 256 + wv * 64) * 16 + lane * 16;
            gload_lds16(g, l);
        }
    };

    stage(0, 0);
    __syncthreads();  // drains vmcnt(0) for buf0
    int cur = 0;
    for (int k0 = 0; k0 < K; k0 += 64) {
        if (k0 + 64 < K) stage(cur ^ 1, k0 + 64);  // prefetch overlaps compute below
        const unsigned short* Ac = As[cur];
        const unsigned short* Bc = Bs[cur];
#pragma unroll
        for (int h = 0; h < 2; ++h) {
            bf16x8 af[MI], bfr[NJ];
#pragma unroll
            for (int i = 0; i < MI; ++i)
                af[i] = *(const bf16x8*)(Ac + (wr * MI * 16 + i * 16 + lm) * 64 +
                                         (((h << 2) + q) ^ sw) * 8);
#pragma unroll
            for (int j = 0; j < NJ; ++j)
                bfr[j] = *(const bf16x8*)(Bc + (wc * NJ * 16 + j * 16 + lm) * 64 +
                                          (((h << 2) + q) ^ sw) * 8);
#pragma unroll
            for (int i = 0; i < MI; ++i)
#pragma unroll
                for (int j = 0; j < NJ; ++j)
                    acc[i][j] = __builtin_amdgcn_mfma_f32_16x16x32_bf16(af[i], bfr[j], acc[i][j], 0, 0, 0);
        }
        __syncthreads();  // drains prefetch vmcnt + release cur buffer
        cur ^= 1;
    }
#pragma unroll
    for (int i = 0; i < MI; ++i) {
#pragma unroll
        for (int j = 0; j < NJ; ++j) {
#pragma unroll
            for (int r = 0; r < 4; ++r) {
                int row = m0 + wr * MI * 16 + i * 16 + q * 4 + r;
                int col = n0 + wc * NJ * 16 + j * 16 + lm;
                float v = acc[i][j][r];
                if (EPI == 0) {  // f32 out + full residual (out_proj)
                    ((float*)Cv)[(size_t)row * ldc + col] = v + res[(size_t)row * ldc + col];
                } else if (EPI == 1) {
                    v += res[col];
                    // fast softplus: v_log_f32/v_exp_f32 intrinsics, not libm log1pf
                    // (rel err ~1e-6; bf16 output quantization 2^-8 dominates)
                    v = (v > 20.f) ? v : __logf(1.f + __expf(v));
                    ((unsigned short*)Cv)[(size_t)row * ldc + col] = (unsigned short)f2bf_u(v);
                } else {  // EPI == 3
                    if (n0 >= D_INNER) v = v * sigmoidf_(v);  // fused silu(z)
                    ((unsigned short*)Cv)[(size_t)row * ldc + col] = (unsigned short)f2bf_u(v);
                }
            }
        }
    }
}

// ---------------- x_proj split-K MFMA GEMM (K-slab 128, 2 K-steps, dbuf) -> bf16 partials ----------------
__global__ __launch_bounds__(256) void xproj_gemm(const unsigned short* __restrict__ A,
                                                  const unsigned short* __restrict__ B,
                                                  unsigned short* __restrict__ part) {
    constexpr int MI = 4, NJ = 4;
    __shared__ __align__(16) unsigned short As[2][128 * 64];
    __shared__ __align__(16) unsigned short Bs[2][128 * 64];
    int tid = threadIdx.x;
    int lane = tid & 63, wv = tid >> 6;
    int wr = wv >> 1, wc = wv & 1;
    int lm = lane & 15, q = lane >> 4;
    int sw = lm & 7;
    int m0 = blockIdx.x * 128;
    int kbase = blockIdx.y * 128;
    f32x4 acc[MI][NJ] = {};

    auto stage = [&](int bufi, int k0) {
#pragma unroll
        for (int it = 0; it < 4; ++it) {
            int chunk = it * 256 + tid;
            int cc = (chunk & 7) ^ ((chunk >> 3) & 7);
            const unsigned short* g = A + (size_t)(m0 + (chunk >> 3)) * D_INNER + k0 + cc * 8;
            char* l = (char*)As[bufi] + (it * 256 + wv * 64) * 16 + lane * 16;
            gload_lds16(g, l);
        }
#pragma unroll
        for (int it = 0; it < 4; ++it) {
            int chunk = it * 256 + tid;
            int cc = (chunk & 7) ^ ((chunk >> 3) & 7);
            const unsigned short* g = B + (size_t)(chunk >> 3) * D_INNER + k0 + cc * 8;
            char* l = (char*)Bs[bufi] + (it * 256 + wv * 64) * 16 + lane * 16;
            gload_lds16(g, l);
        }
    };

    stage(0, kbase);
    __syncthreads();
    for (int ks = 0; ks < 2; ++ks) {
        if (ks == 0) stage(1, kbase + 64);
        const unsigned short* Ac = As[ks];
        const unsigned short* Bc = Bs[ks];
#pragma unroll
        for (int h = 0; h < 2; ++h) {
            bf16x8 af[MI], bfr[NJ];
#pragma unroll
            for (int i = 0; i < MI; ++i)
                af[i] = *(const bf16x8*)(Ac + (wr * 64 + i * 16 + lm) * 64 + (((h << 2) + q) ^ sw) * 8);
#pragma unroll
            for (int j = 0; j < NJ; ++j)
                bfr[j] = *(const bf16x8*)(Bc + (wc * 64 + j * 16 + lm) * 64 + (((h << 2) + q) ^ sw) * 8);
#pragma unroll
            for (int i = 0; i < MI; ++i)
#pragma unroll
                for (int j = 0; j < NJ; ++j)
                    acc[i][j] = __builtin_amdgcn_mfma_f32_16x16x32_bf16(af[i], bfr[j], acc[i][j], 0, 0, 0);
        }
        __syncthreads();
    }
    unsigned short* dst = part + (size_t)blockIdx.y * (NTOK * XPROJ_LD);
#pragma unroll
    for (int i = 0; i < MI; ++i)
#pragma unroll
        for (int j = 0; j < NJ; ++j)
#pragma unroll
            for (int r = 0; r < 4; ++r) {
                int row = m0 + wr * 64 + i * 16 + q * 4 + r;
                int col = wc * 64 + j * 16 + lm;
                dst[(size_t)row * XPROJ_LD + col] = (unsigned short)f2bf_u(acc[i][j][r]);
            }
}

// ---------------- reduce split-K partials (4 elems/thread); emit dbc f32 + dt_raw bf16 ----------------
__global__ __launch_bounds__(256) void k_xred(const unsigned short* __restrict__ part,
                                              float* __restrict__ dbc,
                                              unsigned short* __restrict__ dtrawb) {
    int idx4 = blockIdx.x * 256 + threadIdx.x;  // unit of 4 elems
    float s0 = 0.f, s1 = 0.f, s2 = 0.f, s3 = 0.f;
#pragma unroll
    for (int sp = 0; sp < NSPLIT; ++sp) {
        uint2 v = *(const uint2*)(part + (size_t)sp * (NTOK * XPROJ_LD) + idx4 * 4);
        s0 += __uint_as_float(v.x << 16);
        s1 += __uint_as_float(v.x & 0xFFFF0000u);
        s2 += __uint_as_float(v.y << 16);
        s3 += __uint_as_float(v.y & 0xFFFF0000u);
    }
    float4 sv = {s0, s1, s2, s3};
    *(float4*)(dbc + idx4 * 4) = sv;
    int col = (idx4 * 4) & (XPROJ_LD - 1);
    if (col < DT_RANK) {
        int row = (idx4 * 4) >> 7;
        uint2 o;
        o.x = f2bf_u(s0) | (f2bf_u(s1) << 16);
        o.y = f2bf_u(s2) | (f2bf_u(s3) << 16);
        *(uint2*)(dtrawb + (size_t)row * DT_RANK + col) = o;
    }
}

// ---------------- depthwise causal conv (k=4, bf16 in) + SiLU -> ub, 4 channels/thread ----------------
__global__ __launch_bounds__(256) void k_conv(const unsigned short* __restrict__ xz,
                                              const float* __restrict__ cw,
                                              const float* __restrict__ cb,
                                              unsigned short* __restrict__ ub) {
    int idx = blockIdx.x * 256 + threadIdx.x;
    int c4 = (idx & (D_INNER / 4 - 1)) * 4;
    int t = (idx >> 9) & (T_LEN - 1);
    int b = idx >> 19;
    const unsigned short* xs = xz + (size_t)b * T_LEN * 2 * D_INNER + c4;
    float4 w[4];
#pragma unroll
    for (int i = 0; i < 4; ++i) w[i] = ((const float4*)cw)[c4 + i];
    float4 cbv = *(const float4*)(cb + c4);
    float s[4] = {cbv.x, cbv.y, cbv.z, cbv.w};
#pragma unroll
    for (int k = 0; k < 4; ++k) {
        int tt = t - 3 + k;
        if (tt >= 0) {
            ushort4 xv = *(const ushort4*)(xs + (size_t)tt * 2 * D_INNER);
            float fx0 = bf2f(xv.x), fx1 = bf2f(xv.y), fx2 = bf2f(xv.z), fx3 = bf2f(xv.w);
            float w0 = (k == 0) ? w[0].x : (k == 1) ? w[0].y : (k == 2) ? w[0].z : w[0].w;
            float w1 = (k == 0) ? w[1].x : (k == 1) ? w[1].y : (k == 2) ? w[1].z : w[1].w;
            float w2 = (k == 0) ? w[2].x : (k == 1) ? w[2].y : (k == 2) ? w[2].z : w[2].w;
            float w3 = (k == 0) ? w[3].x : (k == 1) ? w[3].y : (k == 2) ? w[3].z : w[3].w;
            s[0] = fmaf(fx0, w0, s[0]);
            s[1] = fmaf(fx1, w1, s[1]);
            s[2] = fmaf(fx2, w2, s[2]);
            s[3] = fmaf(fx3, w3, s[3]);
        }
    }
    ushort4 o;
    o.x = (unsigned short)f2bf_u(s[0] * sigmoidf_(s[0]));
    o.y = (unsigned short)f2bf_u(s[1] * sigmoidf_(s[1]));
    o.z = (unsigned short)f2bf_u(s[2] * sigmoidf_(s[2]));
    o.w = (unsigned short)f2bf_u(s[3] * sigmoidf_(s[3]));
    *(ushort4*)(ub + (size_t)(b * T_LEN + t) * D_INNER + c4) = o;
}

// ---------------- chunked selective scan, state-parallel: 4 threads/channel ----------------
__global__ __launch_bounds__(256) void k_scan1(const unsigned short* __restrict__ delta,
                                               const unsigned short* __restrict__ ub,
                                               const float* __restrict__ dbc,
                                               const float* __restrict__ A_log,
                                               float* __restrict__ Pbuf,
                                               float* __restrict__ Hbuf) {
    int tid = threadIdx.x;
    int cl = tid >> 2, sq = tid & 3;
    int c0 = blockIdx.x * 64;
    int c = c0 + cl;
    int b = blockIdx.y >> 5, chunk = blockIdx.y & 31;
    int t0 = chunk * CHUNK_L;
    __shared__ float bc[CHUNK_L][32];  // [t][0:16]=B, [t][16:32]=C
    __shared__ __align__(16) unsigned short sd[CHUNK_L][64];
    __shared__ __align__(16) unsigned short su[CHUNK_L][64];
    {
        int t = tid >> 3, col = (tid & 7) * 4;
        const float* src = dbc + ((size_t)b * T_LEN + t0 + t) * XPROJ_LD + DT_RANK + col;
        *(float4*)&bc[t][col] = *(const float4*)src;
    }
    {
        int r = tid >> 3, c8 = (tid & 7) * 8;
        const unsigned short* dp0 = delta + ((size_t)b * T_LEN + t0) * D_INNER + c0;
        const unsigned short* up0 = ub + ((size_t)b * T_LEN + t0) * D_INNER + c0;
        *(uint4*)&sd[r][c8] = *(const uint4*)(dp0 + (size_t)r * D_INNER + c8);
        *(uint4*)&su[r][c8] = *(const uint4*)(up0 + (size_t)r * D_INNER + c8);
    }
    __syncthreads();
    float4 av = *(const float4*)(A_log + (size_t)c * D_STATE + sq * 4);
    float A0 = -__expf(av.x), A1 = -__expf(av.y), A2 = -__expf(av.z), A3 = -__expf(av.w);
    float h0 = 0.f, h1 = 0.f, h2 = 0.f, h3 = 0.f, sumd = 0.f;
#pragma unroll 4
    for (int t = 0; t < CHUNK_L; ++t) {
        float dv = bf2f(sd[t][cl]);
        float uv = bf2f(su[t][cl]);
        float du = dv * uv;
        sumd += dv;
        float4 Bv = *(const float4*)&bc[t][sq * 4];
        h0 = fmaf(__expf(dv * A0), h0, du * Bv.x);
        h1 = fmaf(__expf(dv * A1), h1, du * Bv.y);
        h2 = fmaf(__expf(dv * A2), h2, du * Bv.z);
        h3 = fmaf(__expf(dv * A3), h3, du * Bv.w);
    }
    size_t o = ((size_t)((b * NCHUNK + chunk) * D_INNER) + c) * 16 + sq * 4;
    float4 hv = {h0, h1, h2, h3};
    *(float4*)(Hbuf + o) = hv;
    float4 pv = {__expf(A0 * sumd), __expf(A1 * sumd), __expf(A2 * sumd), __expf(A3 * sumd)};
    *(float4*)(Pbuf + o) = pv;
}

__global__ __launch_bounds__(256) void k_scan2(const float* __restrict__ Pbuf,
                                               const float* __restrict__ Hbuf,
                                               float* __restrict__ Sbuf) {
    int idx = blockIdx.x * 256 + threadIdx.x;  // 0..65535 = (b, c*16+s)
    int b = idx >> 15, r = idx & 32767;
    size_t base = (size_t)b * NCHUNK * (D_INNER * 16) + r;
    float p[NCHUNK], hl[NCHUNK];
#pragma unroll
    for (int ch = 0; ch < NCHUNK; ++ch) {
        size_t o = base + (size_t)ch * (D_INNER * 16);
        p[ch] = Pbuf[o];
        hl[ch] = Hbuf[o];
    }
    float h = 0.f;
#pragma unroll
    for (int ch = 0; ch < NCHUNK; ++ch) {
        Sbuf[base + (size_t)ch * (D_INNER * 16)] = h;
        h = fmaf(p[ch], h, hl[ch]);
    }
}

__global__ __launch_bounds__(256) void k_scan3(const unsigned short* __restrict__ delta,
                                               const unsigned short* __restrict__ ub,
                                               const float* __restrict__ dbc,
                                               const unsigned short* __restrict__ xz,  // z-half pre-silu'd
                                               const float* __restrict__ A_log,
                                               const float* __restrict__ Dp,
                                               const float* __restrict__ Sbuf,
                                               unsigned short* __restrict__ yb) {
    int tid = threadIdx.x;
    int cl = tid >> 2, sq = tid & 3;
    int c0 = blockIdx.x * 64;
    int c = c0 + cl;
    int b = blockIdx.y >> 5, chunk = blockIdx.y & 31;
    int t0 = chunk * CHUNK_L;
    __shared__ float bc[CHUNK_L][32];
    __shared__ __align__(16) unsigned short sd[CHUNK_L][64];
    __shared__ __align__(16) unsigned short su[CHUNK_L][64];
    __shared__ __align__(16) unsigned short szy[CHUNK_L][64];  // z in, y out (in-place)
    {
        int t = tid >> 3, col = (tid & 7) * 4;
        const float* src = dbc + ((size_t)b * T_LEN + t0 + t) * XPROJ_LD + DT_RANK + col;
        *(float4*)&bc[t][col] = *(const float4*)src;
    }
    int r = tid >> 3, c8 = (tid & 7) * 8;
    {
        const unsigned short* dp0 = delta + ((size_t)b * T_LEN + t0) * D_INNER + c0;
        const unsigned short* up0 = ub + ((size_t)b * T_LEN + t0) * D_INNER + c0;
        const unsigned short* zp0 = xz + ((size_t)b * T_LEN + t0) * 2 * D_INNER + D_INNER + c0;
        *(uint4*)&sd[r][c8] = *(const uint4*)(dp0 + (size_t)r * D_INNER + c8);
        *(uint4*)&su[r][c8] = *(const uint4*)(up0 + (size_t)r * D_INNER + c8);
        *(uint4*)&szy[r][c8] = *(const uint4*)(zp0 + (size_t)r * 2 * D_INNER + c8);
    }
    __syncthreads();
    float4 av = *(const float4*)(A_log + (size_t)c * D_STATE + sq * 4);
    float A0 = -__expf(av.x), A1 = -__expf(av.y), A2 = -__expf(av.z), A3 = -__expf(av.w);
    float Dc = Dp[c];
    size_t ho = ((size_t)((b * NCHUNK + chunk) * D_INNER) + c) * 16 + sq * 4;
    float4 hv = *(const float4*)(Sbuf + ho);
    float h0 = hv.x, h1 = hv.y, h2 = hv.z, h3 = hv.w;
#pragma unroll 2
    for (int t = 0; t < CHUNK_L; ++t) {
        float dv = bf2f(sd[t][cl]);
        float uv = bf2f(su[t][cl]);
        float du = dv * uv;
        float4 Bv = *(const float4*)&bc[t][sq * 4];
        float4 Cv = *(const float4*)&bc[t][16 + sq * 4];
        h0 = fmaf(__expf(dv * A0), h0, du * Bv.x);
        h1 = fmaf(__expf(dv * A1), h1, du * Bv.y);
        h2 = fmaf(__expf(dv * A2), h2, du * Bv.z);
        h3 = fmaf(__expf(dv * A3), h3, du * Bv.w);
        float yp = h0 * Cv.x + h1 * Cv.y + h2 * Cv.z + h3 * Cv.w;
        yp += __shfl_xor(yp, 1);
        yp += __shfl_xor(yp, 2);
        if (sq == 0) {
            float sz = bf2f(szy[t][cl]);  // already silu(z)
            szy[t][cl] = (unsigned short)f2bf_u((yp + Dc * uv) * sz);
        }
    }
    __syncthreads();
    {
        unsigned short* yp0 = yb + ((size_t)b * T_LEN + t0) * D_INNER + c0;
        *(uint4*)(yp0 + (size_t)r * D_INNER + c8) = *(uint4*)&szy[r][c8];
    }
}

extern "C" void kernel_launch(void* const* d_in, const int* in_sizes, int n_in,
                              void* d_out, int out_size, void* d_ws, size_t ws_size,
                              hipStream_t stream) {
    const float* x         = (const float*)d_in[0];
    const float* norm_w    = (const float*)d_in[1];
    const float* in_proj_w = (const float*)d_in[2];
    const float* conv_w    = (const float*)d_in[3];
    const float* conv_b    = (const float*)d_in[4];
    const float* x_proj_w  = (const float*)d_in[5];
    const float* dt_proj_w = (const float*)d_in[6];
    const float* dt_proj_b = (const float*)d_in[7];
    const float* A_log     = (const float*)d_in[8];
    const float* D_param   = (const float*)d_in[9];
    const float* out_proj_w= (const float*)d_in[10];
    float* out = (float*)d_out;

    // workspace layout (float units), flat
    float* ws = (float*)d_ws;
    unsigned short* xzb    = (unsigned short*)(ws);            // 2048*4096 bf16 (z-half silu'd)
    unsigned short* ub     = (unsigned short*)(ws + 4194304);  // 2048*2048 bf16
    unsigned short* yb     = (unsigned short*)(ws + 6291456);  // 2048*2048 bf16
    unsigned short* partb  = (unsigned short*)(ws + 8388608);  // 16*2048*128 bf16
    float*          dbc    = ws + 12582912;                    // 2048*128 f32
    unsigned short* deltab = (unsigned short*)(ws + 12845056); // 2048*2048 bf16
    float*          Pbuf   = ws + 14942208;                    // 2*32*2048*16 f32
    float*          Hbuf   = ws + 17039360;                    // 2*32*2048*16 f32
    float*          Sbuf   = ws + 19136512;                    // 2*32*2048*16 f32
    unsigned short* wib    = (unsigned short*)(ws + 21233664); // 4096*1024 bf16
    unsigned short* wob    = (unsigned short*)(ws + 23330816); // 1024*2048 bf16
    unsigned short* wxb    = (unsigned short*)(ws + 24379392); // 128*2048 bf16
    unsigned short* wdtb   = (unsigned short*)(ws + 24510464); // 2048*64 bf16
    unsigned short* dtrawb = (unsigned short*)(ws + 24576000); // 2048*64 bf16
    unsigned short* xnb    = (unsigned short*)(ws + 24641536); // 2048*1024 bf16

    // 0. fused RMSNorm + all weight casts (one launch)
    k_prep<<<5312, 256, 0, stream>>>(x, norm_w, in_proj_w, out_proj_w, x_proj_w, dt_proj_w,
                                     xnb, (unsigned*)wib, (unsigned*)wob, (unsigned*)wxb,
                                     (unsigned*)wdtb);
    // 1. xz = xn @ in_proj_w^T (2048x4096x1024) -> bf16; z-half fused silu (512 blocks)
    gemm_bf16<128, 2, 3><<<dim3(NTOK / 128, 4096 / 128), 256, 0, stream>>>(
        xnb, wib, xzb, 2 * D_INNER, D_MODEL, nullptr);
    // 2. depthwise conv + SiLU -> ub (4 channels/thread, 8B/lane)
    k_conv<<<(NTOK * D_INNER / 4) / 256, 256, 0, stream>>>(xzb, conv_w, conv_b, ub);
    // 3. x_dbc: split-K MFMA GEMM (16 slabs of K=128, 256 blocks, dbuf) + reduce
    xproj_gemm<<<dim3(NTOK / 128, NSPLIT), 256, 0, stream>>>(ub, wxb, partb);
    k_xred<<<(NTOK * XPROJ_LD) / 1024, 256, 0, stream>>>(partb, dbc, dtrawb);
    // 4. delta = softplus(dt_raw @ dt_proj_w^T + b) -> bf16 (BN=64: 512 blocks)
    gemm_bf16<64, 1, 1><<<dim3(NTOK / 128, D_INNER / 64), 256, 0, stream>>>(
        dtrawb, wdtb, deltab, D_INNER, DT_RANK, dt_proj_b);
    // 5. chunked selective scan (3 kernels, state-parallel 4 thr/channel) -> yb
    k_scan1<<<dim3(D_INNER / 64, B_SZ * NCHUNK), 256, 0, stream>>>(deltab, ub, dbc, A_log,
                                                                   Pbuf, Hbuf);
    k_scan2<<<(B_SZ * D_INNER * D_STATE) / 256, 256, 0, stream>>>(Pbuf, Hbuf, Sbuf);
    k_scan3<<<dim3(D_INNER / 64, B_SZ * NCHUNK), 256, 0, stream>>>(deltab, ub, dbc, xzb, A_log,
                                                                   D_param, Sbuf, yb);
    // 6. out = y @ out_proj_w^T + x (2048x1024x2048), 128x64 tiles, dbuf pipeline
    gemm_bf16<64, 2, 0><<<dim3(NTOK / 128, D_MODEL / 64), 256, 0, stream>>>(
        yb, wob, (void*)out, D_MODEL, D_INNER, x);

    (void)in_sizes; (void)n_in; (void)out_size; (void)ws_size;
}

// Round 8
// 218.101 us; speedup vs baseline: 1.0978x; 1.0308x over previous
//
#include <hip/hip_runtime.h>
#include <math.h>

#define B_SZ 2
#define T_LEN 1024
#define D_MODEL 1024
#define D_STATE 16
#define D_INNER 2048
#define DT_RANK 64
#define NTOK (B_SZ * T_LEN)               // 2048 tokens
#define XPROJ_OUT 96
#define XPROJ_LD 128                      // padded leading dim for dbc
#define NCHUNK 32
#define CHUNK_L (T_LEN / NCHUNK)          // 32
#define NSPLIT 16                         // split-K for x_proj (K-slab 128)

typedef __attribute__((ext_vector_type(8))) short bf16x8;
typedef __attribute__((ext_vector_type(4))) float f32x4;

__device__ __forceinline__ float sigmoidf_(float x) { return 1.f / (1.f + __expf(-x)); }

__device__ __forceinline__ unsigned f2bf_u(float f) {  // RNE f32->bf16 bits
    unsigned u = __float_as_uint(f);
    return (u + 0x7FFFu + ((u >> 16) & 1u)) >> 16;
}
__device__ __forceinline__ float bf2f(unsigned short u) {
    return __uint_as_float((unsigned)u << 16);
}

__device__ __forceinline__ void gload_lds16(const void* g, void* l) {
    __builtin_amdgcn_global_load_lds((const __attribute__((address_space(1))) unsigned*)g,
                                     (__attribute__((address_space(3))) unsigned*)l,
                                     16, 0, 0);
}

// ---------------- fused prep: RMSNorm + all weight casts, one launch ----------------
__global__ __launch_bounds__(256) void k_prep(const float* __restrict__ x,
                                              const float* __restrict__ norm_w,
                                              const float* __restrict__ w_in,
                                              const float* __restrict__ w_out,
                                              const float* __restrict__ w_x,
                                              const float* __restrict__ w_dt,
                                              unsigned short* __restrict__ xn,
                                              unsigned* __restrict__ wib,
                                              unsigned* __restrict__ wob,
                                              unsigned* __restrict__ wxb,
                                              unsigned* __restrict__ wdtb) {
    __shared__ float red[4];
    int blk = blockIdx.x;
    if (blk < 2048) {  // RMSNorm row
        const float* xr = x + (size_t)blk * D_MODEL;
        int i = threadIdx.x * 4;
        float4 xv = *(const float4*)(xr + i);
        float s = xv.x * xv.x + xv.y * xv.y + xv.z * xv.z + xv.w * xv.w;
#pragma unroll
        for (int m = 1; m <= 32; m <<= 1) s += __shfl_xor(s, m);
        if ((threadIdx.x & 63) == 0) red[threadIdx.x >> 6] = s;
        __syncthreads();
        float tot = red[0] + red[1] + red[2] + red[3];
        float scale = rsqrtf(tot * (1.f / D_MODEL) + 1.1920929e-07f);
        float4 wv = *(const float4*)(norm_w + i);
        uint2 o;
        o.x = f2bf_u(xv.x * scale * wv.x) | (f2bf_u(xv.y * scale * wv.y) << 16);
        o.y = f2bf_u(xv.z * scale * wv.z) | (f2bf_u(xv.w * scale * wv.w) << 16);
        *(uint2*)(xn + (size_t)blk * D_MODEL + i) = o;
        return;
    }
    blk -= 2048;
    const float* src;
    unsigned* dst;
    int lidx;  // index in units of 8 elems
    if (blk < 2048) {
        src = w_in; dst = wib; lidx = blk * 256 + threadIdx.x;
    } else if (blk < 3072) {
        src = w_out; dst = wob; lidx = (blk - 2048) * 256 + threadIdx.x;
    } else if (blk < 3200) {
        dst = wxb; lidx = (blk - 3072) * 256 + threadIdx.x;
        if (lidx * 8 >= 96 * 2048) {  // pad rows 96..127 with zeros
            uint4 z = {0, 0, 0, 0};
            ((uint4*)dst)[lidx] = z;
            return;
        }
        src = w_x;
    } else {
        src = w_dt; dst = wdtb; lidx = (blk - 3200) * 256 + threadIdx.x;
    }
    float4 a = ((const float4*)src)[lidx * 2];
    float4 b = ((const float4*)src)[lidx * 2 + 1];
    uint4 o;
    o.x = f2bf_u(a.x) | (f2bf_u(a.y) << 16);
    o.y = f2bf_u(a.z) | (f2bf_u(a.w) << 16);
    o.z = f2bf_u(b.x) | (f2bf_u(b.y) << 16);
    o.w = f2bf_u(b.z) | (f2bf_u(b.w) << 16);
    ((uint4*)dst)[lidx] = o;
}

// XOR-swizzled LDS tile layout (rows of 64 bf16 = 8 chunks of 16B):
//   slot(r, c) = r*8 + (c ^ (r & 7))   — spreads fragment reads over all 32 banks.

// ---------------- bf16 MFMA GEMM, BM=128, BK=64, dbuf K-loop + LDS-staged epilogue ----------------
// EPI: 0 = f32 out + per-element residual (float4 path); 1 = softplus(v+res[col]) bf16;
//      3 = bf16 out, silu when n0 >= D_INNER.
// Epilogue: acc -> LDS tile (padded stride) -> cooperative uint4/float4 coalesced stores
// (replaces 32 scalar 2B stores/thread with 4-8 16B stores; R4 probe: GEMM cores <=13.6us,
//  the un-REP'd epilogues are the remaining cost, cf. dt_proj log1pf -15us in R7).
template <int BN, int CW, int EPI>
__global__ __launch_bounds__(256) void gemm_bf16(const unsigned short* __restrict__ A,
                                                 const unsigned short* __restrict__ B,
                                                 void* __restrict__ Cv, int ldc, int K,
                                                 const float* __restrict__ res) {
    constexpr int RW = 4 / CW;
    constexpr int MI = (128 / RW) / 16;
    constexpr int NJ = (BN / CW) / 16;
    __shared__ __align__(16) unsigned short smem[2 * 128 * 64 + 2 * BN * 64];
    unsigned short* As0 = smem;
    unsigned short* Bs0 = smem + 2 * 128 * 64;
    int tid = threadIdx.x;
    int lane = tid & 63, wv = tid >> 6;
    int wr = wv / CW, wc = wv % CW;
    int lm = lane & 15, q = lane >> 4;
    int sw = lm & 7;
    int m0 = blockIdx.x * 128, n0 = blockIdx.y * BN;
    f32x4 acc[MI][NJ] = {};

    auto stage = [&](int bufi, int k0) {
#pragma unroll
        for (int it = 0; it < 4; ++it) {
            int chunk = it * 256 + tid;
            int cc = (chunk & 7) ^ ((chunk >> 3) & 7);  // swizzled source column-chunk
            const unsigned short* g = A + (size_t)(m0 + (chunk >> 3)) * K + k0 + cc * 8;
            char* l = (char*)(As0 + bufi * 128 * 64) + (it * 256 + wv * 64) * 16 + lane * 16;
            gload_lds16(g, l);
        }
#pragma unroll
        for (int it = 0; it < BN / 32; ++it) {
            int chunk = it * 256 + tid;
            int cc = (chunk & 7) ^ ((chunk >> 3) & 7);
            const unsigned short* g = B + (size_t)(n0 + (chunk >> 3)) * K + k0 + cc * 8;
            char* l = (char*)(Bs0 + bufi * BN * 64) + (it * 256 + wv * 64) * 16 + lane * 16;
            gload_lds16(g, l);
        }
    };

    stage(0, 0);
    __syncthreads();  // drains vmcnt(0) for buf0
    int cur = 0;
    for (int k0 = 0; k0 < K; k0 += 64) {
        if (k0 + 64 < K) stage(cur ^ 1, k0 + 64);  // prefetch overlaps compute below
        const unsigned short* Ac = As0 + cur * 128 * 64;
        const unsigned short* Bc = Bs0 + cur * BN * 64;
#pragma unroll
        for (int h = 0; h < 2; ++h) {
            bf16x8 af[MI], bfr[NJ];
#pragma unroll
            for (int i = 0; i < MI; ++i)
                af[i] = *(const bf16x8*)(Ac + (wr * MI * 16 + i * 16 + lm) * 64 +
                                         (((h << 2) + q) ^ sw) * 8);
#pragma unroll
            for (int j = 0; j < NJ; ++j)
                bfr[j] = *(const bf16x8*)(Bc + (wc * NJ * 16 + j * 16 + lm) * 64 +
                                          (((h << 2) + q) ^ sw) * 8);
#pragma unroll
            for (int i = 0; i < MI; ++i)
#pragma unroll
                for (int j = 0; j < NJ; ++j)
                    acc[i][j] = __builtin_amdgcn_mfma_f32_16x16x32_bf16(af[i], bfr[j], acc[i][j], 0, 0, 0);
        }
        __syncthreads();  // drains prefetch vmcnt + release cur buffer
        cur ^= 1;
    }
    // ---- epilogue: reg -> padded LDS tile -> cooperative wide stores ----
    if (EPI == 0) {
        constexpr int LDT = BN + 8;  // f32 elems; +8 dwords -> +8 banks/row, conflict-free
        float* Ct = (float*)smem;    // [128][LDT] = 36864 B <= smem bytes (49152 @ BN=64)
#pragma unroll
        for (int i = 0; i < MI; ++i)
#pragma unroll
            for (int j = 0; j < NJ; ++j)
#pragma unroll
                for (int r = 0; r < 4; ++r) {
                    int lr = wr * MI * 16 + i * 16 + q * 4 + r;
                    int lc = wc * NJ * 16 + j * 16 + lm;
                    Ct[lr * LDT + lc] = acc[i][j][r];
                }
        __syncthreads();
        int r0 = tid >> 4, c4 = (tid & 15) * 4;
#pragma unroll
        for (int rr = 0; rr < 8; ++rr) {
            int lr = r0 + rr * 16;
            float4 v = *(float4*)&Ct[lr * LDT + c4];
            float4 rv = *(const float4*)&res[(size_t)(m0 + lr) * ldc + n0 + c4];
            v.x += rv.x; v.y += rv.y; v.z += rv.z; v.w += rv.w;
            *(float4*)&((float*)Cv)[(size_t)(m0 + lr) * ldc + n0 + c4] = v;
        }
    } else {
        constexpr int LDT = BN + 16;  // bf16 elems; +8 banks/row
        unsigned short* Ct = smem;    // [128][LDT] <= 36864 B, fits both BN
#pragma unroll
        for (int i = 0; i < MI; ++i)
#pragma unroll
            for (int j = 0; j < NJ; ++j)
#pragma unroll
                for (int r = 0; r < 4; ++r) {
                    int lr = wr * MI * 16 + i * 16 + q * 4 + r;
                    int lc = wc * NJ * 16 + j * 16 + lm;
                    float v = acc[i][j][r];
                    if (EPI == 1) {
                        v += res[n0 + lc];
                        // fast softplus: v_log/v_exp intrinsics (rel err ~1e-6 << bf16 quant)
                        v = (v > 20.f) ? v : __logf(1.f + __expf(v));
                    } else {  // EPI == 3
                        if (n0 >= D_INNER) v = v * sigmoidf_(v);  // fused silu(z)
                    }
                    Ct[lr * LDT + lc] = (unsigned short)f2bf_u(v);
                }
        __syncthreads();
        constexpr int CW8 = BN / 8;            // uint4 chunks per row
        constexpr int RPP = 256 / CW8;         // rows per pass
        int r0 = tid / CW8, cc = (tid % CW8) * 8;
#pragma unroll
        for (int rr = 0; rr < 128 / RPP; ++rr) {
            int lr = r0 + rr * RPP;
            uint4 v = *(uint4*)&Ct[lr * LDT + cc];
            *(uint4*)&((unsigned short*)Cv)[(size_t)(m0 + lr) * ldc + n0 + cc] = v;
        }
    }
}

// ---------------- x_proj split-K MFMA GEMM (K-slab 128, dbuf) + LDS-staged epilogue ----------------
__global__ __launch_bounds__(256) void xproj_gemm(const unsigned short* __restrict__ A,
                                                  const unsigned short* __restrict__ B,
                                                  unsigned short* __restrict__ part) {
    constexpr int MI = 4, NJ = 4;
    __shared__ __align__(16) unsigned short smem[4 * 128 * 64];
    unsigned short* As0 = smem;
    unsigned short* Bs0 = smem + 2 * 128 * 64;
    int tid = threadIdx.x;
    int lane = tid & 63, wv = tid >> 6;
    int wr = wv >> 1, wc = wv & 1;
    int lm = lane & 15, q = lane >> 4;
    int sw = lm & 7;
    int m0 = blockIdx.x * 128;
    int kbase = blockIdx.y * 128;
    f32x4 acc[MI][NJ] = {};

    auto stage = [&](int bufi, int k0) {
#pragma unroll
        for (int it = 0; it < 4; ++it) {
            int chunk = it * 256 + tid;
            int cc = (chunk & 7) ^ ((chunk >> 3) & 7);
            const unsigned short* g = A + (size_t)(m0 + (chunk >> 3)) * D_INNER + k0 + cc * 8;
            char* l = (char*)(As0 + bufi * 128 * 64) + (it * 256 + wv * 64) * 16 + lane * 16;
            gload_lds16(g, l);
        }
#pragma unroll
        for (int it = 0; it < 4; ++it) {
            int chunk = it * 256 + tid;
            int cc = (chunk & 7) ^ ((chunk >> 3) & 7);
            const unsigned short* g = B + (size_t)(chunk >> 3) * D_INNER + k0 + cc * 8;
            char* l = (char*)(Bs0 + bufi * 128 * 64) + (it * 256 + wv * 64) * 16 + lane * 16;
            gload_lds16(g, l);
        }
    };

    stage(0, kbase);
    __syncthreads();
    for (int ks = 0; ks < 2; ++ks) {
        if (ks == 0) stage(1, kbase + 64);
        const unsigned short* Ac = As0 + ks * 128 * 64;
        const unsigned short* Bc = Bs0 + ks * 128 * 64;
#pragma unroll
        for (int h = 0; h < 2; ++h) {
            bf16x8 af[MI], bfr[NJ];
#pragma unroll
            for (int i = 0; i < MI; ++i)
                af[i] = *(const bf16x8*)(Ac + (wr * 64 + i * 16 + lm) * 64 + (((h << 2) + q) ^ sw) * 8);
#pragma unroll
            for (int j = 0; j < NJ; ++j)
                bfr[j] = *(const bf16x8*)(Bc + (wc * 64 + j * 16 + lm) * 64 + (((h << 2) + q) ^ sw) * 8);
#pragma unroll
            for (int i = 0; i < MI; ++i)
#pragma unroll
                for (int j = 0; j < NJ; ++j)
                    acc[i][j] = __builtin_amdgcn_mfma_f32_16x16x32_bf16(af[i], bfr[j], acc[i][j], 0, 0, 0);
        }
        __syncthreads();
    }
    // LDS-staged epilogue -> coalesced uint4 stores of the 128x128 partial tile
    constexpr int LDT = 144;
    unsigned short* Ct = smem;
#pragma unroll
    for (int i = 0; i < MI; ++i)
#pragma unroll
        for (int j = 0; j < NJ; ++j)
#pragma unroll
            for (int r = 0; r < 4; ++r) {
                int lr = wr * 64 + i * 16 + q * 4 + r;
                int lc = wc * 64 + j * 16 + lm;
                Ct[lr * LDT + lc] = (unsigned short)f2bf_u(acc[i][j][r]);
            }
    __syncthreads();
    unsigned short* dst = part + (size_t)blockIdx.y * (NTOK * XPROJ_LD);
    int r0 = tid >> 4, cc = (tid & 15) * 8;
#pragma unroll
    for (int rr = 0; rr < 8; ++rr) {
        int lr = r0 + rr * 16;
        uint4 v = *(uint4*)&Ct[lr * LDT + cc];
        *(uint4*)&dst[(size_t)(m0 + lr) * XPROJ_LD + cc] = v;
    }
}

// ---------------- reduce split-K partials (4 elems/thread); emit dbc f32 + dt_raw bf16 ----------------
__global__ __launch_bounds__(256) void k_xred(const unsigned short* __restrict__ part,
                                              float* __restrict__ dbc,
                                              unsigned short* __restrict__ dtrawb) {
    int idx4 = blockIdx.x * 256 + threadIdx.x;  // unit of 4 elems
    float s0 = 0.f, s1 = 0.f, s2 = 0.f, s3 = 0.f;
#pragma unroll
    for (int sp = 0; sp < NSPLIT; ++sp) {
        uint2 v = *(const uint2*)(part + (size_t)sp * (NTOK * XPROJ_LD) + idx4 * 4);
        s0 += __uint_as_float(v.x << 16);
        s1 += __uint_as_float(v.x & 0xFFFF0000u);
        s2 += __uint_as_float(v.y << 16);
        s3 += __uint_as_float(v.y & 0xFFFF0000u);
    }
    float4 sv = {s0, s1, s2, s3};
    *(float4*)(dbc + idx4 * 4) = sv;
    int col = (idx4 * 4) & (XPROJ_LD - 1);
    if (col < DT_RANK) {
        int row = (idx4 * 4) >> 7;
        uint2 o;
        o.x = f2bf_u(s0) | (f2bf_u(s1) << 16);
        o.y = f2bf_u(s2) | (f2bf_u(s3) << 16);
        *(uint2*)(dtrawb + (size_t)row * DT_RANK + col) = o;
    }
}

// ---------------- depthwise causal conv (k=4, bf16 in) + SiLU -> ub, 4 channels/thread ----------------
__global__ __launch_bounds__(256) void k_conv(const unsigned short* __restrict__ xz,
                                              const float* __restrict__ cw,
                                              const float* __restrict__ cb,
                                              unsigned short* __restrict__ ub) {
    int idx = blockIdx.x * 256 + threadIdx.x;
    int c4 = (idx & (D_INNER / 4 - 1)) * 4;
    int t = (idx >> 9) & (T_LEN - 1);
    int b = idx >> 19;
    const unsigned short* xs = xz + (size_t)b * T_LEN * 2 * D_INNER + c4;
    float4 w[4];
#pragma unroll
    for (int i = 0; i < 4; ++i) w[i] = ((const float4*)cw)[c4 + i];
    float4 cbv = *(const float4*)(cb + c4);
    float s[4] = {cbv.x, cbv.y, cbv.z, cbv.w};
#pragma unroll
    for (int k = 0; k < 4; ++k) {
        int tt = t - 3 + k;
        if (tt >= 0) {
            ushort4 xv = *(const ushort4*)(xs + (size_t)tt * 2 * D_INNER);
            float fx0 = bf2f(xv.x), fx1 = bf2f(xv.y), fx2 = bf2f(xv.z), fx3 = bf2f(xv.w);
            float w0 = (k == 0) ? w[0].x : (k == 1) ? w[0].y : (k == 2) ? w[0].z : w[0].w;
            float w1 = (k == 0) ? w[1].x : (k == 1) ? w[1].y : (k == 2) ? w[1].z : w[1].w;
            float w2 = (k == 0) ? w[2].x : (k == 1) ? w[2].y : (k == 2) ? w[2].z : w[2].w;
            float w3 = (k == 0) ? w[3].x : (k == 1) ? w[3].y : (k == 2) ? w[3].z : w[3].w;
            s[0] = fmaf(fx0, w0, s[0]);
            s[1] = fmaf(fx1, w1, s[1]);
            s[2] = fmaf(fx2, w2, s[2]);
            s[3] = fmaf(fx3, w3, s[3]);
        }
    }
    ushort4 o;
    o.x = (unsigned short)f2bf_u(s[0] * sigmoidf_(s[0]));
    o.y = (unsigned short)f2bf_u(s[1] * sigmoidf_(s[1]));
    o.z = (unsigned short)f2bf_u(s[2] * sigmoidf_(s[2]));
    o.w = (unsigned short)f2bf_u(s[3] * sigmoidf_(s[3]));
    *(ushort4*)(ub + (size_t)(b * T_LEN + t) * D_INNER + c4) = o;
}

// ---------------- chunked selective scan, state-parallel: 4 threads/channel ----------------
__global__ __launch_bounds__(256) void k_scan1(const unsigned short* __restrict__ delta,
                                               const unsigned short* __restrict__ ub,
                                               const float* __restrict__ dbc,
                                               const float* __restrict__ A_log,
                                               float* __restrict__ Pbuf,
                                               float* __restrict__ Hbuf) {
    int tid = threadIdx.x;
    int cl = tid >> 2, sq = tid & 3;
    int c0 = blockIdx.x * 64;
    int c = c0 + cl;
    int b = blockIdx.y >> 5, chunk = blockIdx.y & 31;
    int t0 = chunk * CHUNK_L;
    __shared__ float bc[CHUNK_L][32];  // [t][0:16]=B, [t][16:32]=C
    __shared__ __align__(16) unsigned short sd[CHUNK_L][64];
    __shared__ __align__(16) unsigned short su[CHUNK_L][64];
    {
        int t = tid >> 3, col = (tid & 7) * 4;
        const float* src = dbc + ((size_t)b * T_LEN + t0 + t) * XPROJ_LD + DT_RANK + col;
        *(float4*)&bc[t][col] = *(const float4*)src;
    }
    {
        int r = tid >> 3, c8 = (tid & 7) * 8;
        const unsigned short* dp0 = delta + ((size_t)b * T_LEN + t0) * D_INNER + c0;
        const unsigned short* up0 = ub + ((size_t)b * T_LEN + t0) * D_INNER + c0;
        *(uint4*)&sd[r][c8] = *(const uint4*)(dp0 + (size_t)r * D_INNER + c8);
        *(uint4*)&su[r][c8] = *(const uint4*)(up0 + (size_t)r * D_INNER + c8);
    }
    __syncthreads();
    float4 av = *(const float4*)(A_log + (size_t)c * D_STATE + sq * 4);
    float A0 = -__expf(av.x), A1 = -__expf(av.y), A2 = -__expf(av.z), A3 = -__expf(av.w);
    float h0 = 0.f, h1 = 0.f, h2 = 0.f, h3 = 0.f, sumd = 0.f;
#pragma unroll 4
    for (int t = 0; t < CHUNK_L; ++t) {
        float dv = bf2f(sd[t][cl]);
        float uv = bf2f(su[t][cl]);
        float du = dv * uv;
        sumd += dv;
        float4 Bv = *(const float4*)&bc[t][sq * 4];
        h0 = fmaf(__expf(dv * A0), h0, du * Bv.x);
        h1 = fmaf(__expf(dv * A1), h1, du * Bv.y);
        h2 = fmaf(__expf(dv * A2), h2, du * Bv.z);
        h3 = fmaf(__expf(dv * A3), h3, du * Bv.w);
    }
    size_t o = ((size_t)((b * NCHUNK + chunk) * D_INNER) + c) * 16 + sq * 4;
    float4 hv = {h0, h1, h2, h3};
    *(float4*)(Hbuf + o) = hv;
    float4 pv = {__expf(A0 * sumd), __expf(A1 * sumd), __expf(A2 * sumd), __expf(A3 * sumd)};
    *(float4*)(Pbuf + o) = pv;
}

__global__ __launch_bounds__(256) void k_scan2(const float* __restrict__ Pbuf,
                                               const float* __restrict__ Hbuf,
                                               float* __restrict__ Sbuf) {
    int idx = blockIdx.x * 256 + threadIdx.x;  // 0..65535 = (b, c*16+s)
    int b = idx >> 15, r = idx & 32767;
    size_t base = (size_t)b * NCHUNK * (D_INNER * 16) + r;
    float p[NCHUNK], hl[NCHUNK];
#pragma unroll
    for (int ch = 0; ch < NCHUNK; ++ch) {
        size_t o = base + (size_t)ch * (D_INNER * 16);
        p[ch] = Pbuf[o];
        hl[ch] = Hbuf[o];
    }
    float h = 0.f;
#pragma unroll
    for (int ch = 0; ch < NCHUNK; ++ch) {
        Sbuf[base + (size_t)ch * (D_INNER * 16)] = h;
        h = fmaf(p[ch], h, hl[ch]);
    }
}

__global__ __launch_bounds__(256) void k_scan3(const unsigned short* __restrict__ delta,
                                               const unsigned short* __restrict__ ub,
                                               const float* __restrict__ dbc,
                                               const unsigned short* __restrict__ xz,  // z-half pre-silu'd
                                               const float* __restrict__ A_log,
                                               const float* __restrict__ Dp,
                                               const float* __restrict__ Sbuf,
                                               unsigned short* __restrict__ yb) {
    int tid = threadIdx.x;
    int cl = tid >> 2, sq = tid & 3;
    int c0 = blockIdx.x * 64;
    int c = c0 + cl;
    int b = blockIdx.y >> 5, chunk = blockIdx.y & 31;
    int t0 = chunk * CHUNK_L;
    __shared__ float bc[CHUNK_L][32];
    __shared__ __align__(16) unsigned short sd[CHUNK_L][64];
    __shared__ __align__(16) unsigned short su[CHUNK_L][64];
    __shared__ __align__(16) unsigned short szy[CHUNK_L][64];  // z in, y out (in-place)
    {
        int t = tid >> 3, col = (tid & 7) * 4;
        const float* src = dbc + ((size_t)b * T_LEN + t0 + t) * XPROJ_LD + DT_RANK + col;
        *(float4*)&bc[t][col] = *(const float4*)src;
    }
    int r = tid >> 3, c8 = (tid & 7) * 8;
    {
        const unsigned short* dp0 = delta + ((size_t)b * T_LEN + t0) * D_INNER + c0;
        const unsigned short* up0 = ub + ((size_t)b * T_LEN + t0) * D_INNER + c0;
        const unsigned short* zp0 = xz + ((size_t)b * T_LEN + t0) * 2 * D_INNER + D_INNER + c0;
        *(uint4*)&sd[r][c8] = *(const uint4*)(dp0 + (size_t)r * D_INNER + c8);
        *(uint4*)&su[r][c8] = *(const uint4*)(up0 + (size_t)r * D_INNER + c8);
        *(uint4*)&szy[r][c8] = *(const uint4*)(zp0 + (size_t)r * 2 * D_INNER + c8);
    }
    __syncthreads();
    float4 av = *(const float4*)(A_log + (size_t)c * D_STATE + sq * 4);
    float A0 = -__expf(av.x), A1 = -__expf(av.y), A2 = -__expf(av.z), A3 = -__expf(av.w);
    float Dc = Dp[c];
    size_t ho = ((size_t)((b * NCHUNK + chunk) * D_INNER) + c) * 16 + sq * 4;
    float4 hv = *(const float4*)(Sbuf + ho);
    float h0 = hv.x, h1 = hv.y, h2 = hv.z, h3 = hv.w;
#pragma unroll 2
    for (int t = 0; t < CHUNK_L; ++t) {
        float dv = bf2f(sd[t][cl]);
        float uv = bf2f(su[t][cl]);
        float du = dv * uv;
        float4 Bv = *(const float4*)&bc[t][sq * 4];
        float4 Cv = *(const float4*)&bc[t][16 + sq * 4];
        h0 = fmaf(__expf(dv * A0), h0, du * Bv.x);
        h1 = fmaf(__expf(dv * A1), h1, du * Bv.y);
        h2 = fmaf(__expf(dv * A2), h2, du * Bv.z);
        h3 = fmaf(__expf(dv * A3), h3, du * Bv.w);
        float yp = h0 * Cv.x + h1 * Cv.y + h2 * Cv.z + h3 * Cv.w;
        yp += __shfl_xor(yp, 1);
        yp += __shfl_xor(yp, 2);
        if (sq == 0) {
            float sz = bf2f(szy[t][cl]);  // already silu(z)
            szy[t][cl] = (unsigned short)f2bf_u((yp + Dc * uv) * sz);
        }
    }
    __syncthreads();
    {
        unsigned short* yp0 = yb + ((size_t)b * T_LEN + t0) * D_INNER + c0;
        *(uint4*)(yp0 + (size_t)r * D_INNER + c8) = *(uint4*)&szy[r][c8];
    }
}

extern "C" void kernel_launch(void* const* d_in, const int* in_sizes, int n_in,
                              void* d_out, int out_size, void* d_ws, size_t ws_size,
                              hipStream_t stream) {
    const float* x         = (const float*)d_in[0];
    const float* norm_w    = (const float*)d_in[1];
    const float* in_proj_w = (const float*)d_in[2];
    const float* conv_w    = (const float*)d_in[3];
    const float* conv_b    = (const float*)d_in[4];
    const float* x_proj_w  = (const float*)d_in[5];
    const float* dt_proj_w = (const float*)d_in[6];
    const float* dt_proj_b = (const float*)d_in[7];
    const float* A_log     = (const float*)d_in[8];
    const float* D_param   = (const float*)d_in[9];
    const float* out_proj_w= (const float*)d_in[10];
    float* out = (float*)d_out;

    // workspace layout (float units), flat
    float* ws = (float*)d_ws;
    unsigned short* xzb    = (unsigned short*)(ws);            // 2048*4096 bf16 (z-half silu'd)
    unsigned short* ub     = (unsigned short*)(ws + 4194304);  // 2048*2048 bf16
    unsigned short* yb     = (unsigned short*)(ws + 6291456);  // 2048*2048 bf16
    unsigned short* partb  = (unsigned short*)(ws + 8388608);  // 16*2048*128 bf16
    float*          dbc    = ws + 12582912;                    // 2048*128 f32
    unsigned short* deltab = (unsigned short*)(ws + 12845056); // 2048*2048 bf16
    float*          Pbuf   = ws + 14942208;                    // 2*32*2048*16 f32
    float*          Hbuf   = ws + 17039360;                    // 2*32*2048*16 f32
    float*          Sbuf   = ws + 19136512;                    // 2*32*2048*16 f32
    unsigned short* wib    = (unsigned short*)(ws + 21233664); // 4096*1024 bf16
    unsigned short* wob    = (unsigned short*)(ws + 23330816); // 1024*2048 bf16
    unsigned short* wxb    = (unsigned short*)(ws + 24379392); // 128*2048 bf16
    unsigned short* wdtb   = (unsigned short*)(ws + 24510464); // 2048*64 bf16
    unsigned short* dtrawb = (unsigned short*)(ws + 24576000); // 2048*64 bf16
    unsigned short* xnb    = (unsigned short*)(ws + 24641536); // 2048*1024 bf16

    // 0. fused RMSNorm + all weight casts (one launch)
    k_prep<<<5312, 256, 0, stream>>>(x, norm_w, in_proj_w, out_proj_w, x_proj_w, dt_proj_w,
                                     xnb, (unsigned*)wib, (unsigned*)wob, (unsigned*)wxb,
                                     (unsigned*)wdtb);
    // 1. xz = xn @ in_proj_w^T (2048x4096x1024) -> bf16; z-half fused silu (512 blocks)
    gemm_bf16<128, 2, 3><<<dim3(NTOK / 128, 4096 / 128), 256, 0, stream>>>(
        xnb, wib, xzb, 2 * D_INNER, D_MODEL, nullptr);
    // 2. depthwise conv + SiLU -> ub (4 channels/thread, 8B/lane)
    k_conv<<<(NTOK * D_INNER / 4) / 256, 256, 0, stream>>>(xzb, conv_w, conv_b, ub);
    // 3. x_dbc: split-K MFMA GEMM (16 slabs of K=128, 256 blocks, dbuf) + reduce
    xproj_gemm<<<dim3(NTOK / 128, NSPLIT), 256, 0, stream>>>(ub, wxb, partb);
    k_xred<<<(NTOK * XPROJ_LD) / 1024, 256, 0, stream>>>(partb, dbc, dtrawb);
    // 4. delta = softplus(dt_raw @ dt_proj_w^T + b) -> bf16 (BN=64: 512 blocks)
    gemm_bf16<64, 1, 1><<<dim3(NTOK / 128, D_INNER / 64), 256, 0, stream>>>(
        dtrawb, wdtb, deltab, D_INNER, DT_RANK, dt_proj_b);
    // 5. chunked selective scan (3 kernels, state-parallel 4 thr/channel) -> yb
    k_scan1<<<dim3(D_INNER / 64, B_SZ * NCHUNK), 256, 0, stream>>>(deltab, ub, dbc, A_log,
                                                                   Pbuf, Hbuf);
    k_scan2<<<(B_SZ * D_INNER * D_STATE) / 256, 256, 0, stream>>>(Pbuf, Hbuf, Sbuf);
    k_scan3<<<dim3(D_INNER / 64, B_SZ * NCHUNK), 256, 0, stream>>>(deltab, ub, dbc, xzb, A_log,
                                                                   D_param, Sbuf, yb);
    // 6. out = y @ out_proj_w^T + x (2048x1024x2048), 128x64 tiles, dbuf + LDS epilogue
    gemm_bf16<64, 2, 0><<<dim3(NTOK / 128, D_MODEL / 64), 256, 0, stream>>>(
        yb, wob, (void*)out, D_MODEL, D_INNER, x);

    (void)in_sizes; (void)n_in; (void)out_size; (void)ws_size;
}